// Round 5
// baseline (339.241 us; speedup 1.0000x reference)
//
#include <hip/hip_runtime.h>
#include <hip/hip_bf16.h>
#include <stdint.h>

#define NIMG 32
#define CHN 256
#define HW 56
#define PH 58
#define XP_ELEMS ((size_t)NIMG*PH*PH*CHN)     // 27,557,888 bf16
#define WT_ELEMS ((size_t)9*CHN*CHN)          // 589,824 bf16
#define OUT_ELEMS ((size_t)NIMG*CHN*HW*HW)    // 25,690,112
#define NKT 36                                // K = 2304 = 36 tiles of 64

typedef __attribute__((ext_vector_type(8))) short short8;
typedef __attribute__((ext_vector_type(4))) float floatx4;

#define GLDS(gp, lbyte) __builtin_amdgcn_global_load_lds( \
    (const __attribute__((address_space(1))) void*)(gp), \
    (__attribute__((address_space(3))) void*)((char*)L + (lbyte)), 16, 0, 0)

__device__ inline unsigned short f2bf(float f) {
    union { float f; uint32_t u; } v; v.f = f;
    uint32_t u = v.u;
    return (unsigned short)((u + 0x7FFFu + ((u >> 16) & 1u)) >> 16);  // RNE
}

// ---- weights (flat OIHW fp32) -> sign() bf16, layout [rs][ko][c] ----
__global__ void wprep(const float* __restrict__ wflat, unsigned short* __restrict__ Wt) {
    int o = blockIdx.x * 256 + threadIdx.x;            // < 589824, output-ordered
    int rs = o >> 16, ko = (o >> 8) & 255, c = o & 255;
    float w = wflat[ko * 2304 + c * 9 + rs];
    Wt[o] = (w > 0.f) ? 0x3F80u : (w < 0.f ? 0xBF80u : 0u);
}

// ---- zero only the halo of Xp (replaces 55 MB memset with 3.7 MB) ----
__global__ void halo_zero(unsigned short* __restrict__ Xp) {
    int idx = blockIdx.x * 256 + threadIdx.x;           // < 32*228*128 (uint writes)
    int c2 = idx & 127;
    int t  = idx >> 7;
    int ci = t % 228, n = t / 228;
    int h, w;
    if (ci < 58)       { h = 0;        w = ci; }
    else if (ci < 116) { h = 57;       w = ci - 58; }
    else if (ci < 172) { h = ci - 115; w = 0; }        // h = 1..56
    else               { h = ci - 171; w = 57; }
    *(uint32_t*)&Xp[(((size_t)n * PH + h) * PH + w) * CHN + c2 * 2] = 0u;
}

// ---- x NCHW fp32 -> padded NHWC bf16 (interior only; halo via halo_zero) ----
__global__ void xprep(const float* __restrict__ x, unsigned short* __restrict__ Xp) {
    __shared__ unsigned short tile[56 * 264];          // pitch 264 (16B-aligned rows)
    int b = blockIdx.x;                                 // one (n,h) row per block
    int n = b / 56, h = b - n * 56;
    const float* xr = x + ((size_t)n * CHN) * (HW*HW) + h * HW;
    int tid = threadIdx.x;
    #pragma unroll 4
    for (int it = 0; it < 28; ++it) {
        int i = it * 256 + tid;                         // (c2, w): c2<128, w<56
        int c2 = i / 56, w = i - c2 * 56, c = c2 * 2;
        float f0 = xr[(size_t)c * 3136 + w];
        float f1 = xr[(size_t)(c + 1) * 3136 + w];
        uint32_t u = (uint32_t)f2bf(f0) | ((uint32_t)f2bf(f1) << 16);
        *(uint32_t*)&tile[w * 264 + c] = u;
    }
    __syncthreads();
    unsigned short* op = Xp + (((size_t)n * PH + (h + 1)) * PH + 1) * CHN;
    #pragma unroll
    for (int it = 0; it < 7; ++it) {
        int chunk = it * 256 + tid;
        int w = chunk >> 5, c0 = (chunk & 31) * 8;
        short8 v = *(const short8*)&tile[w * 264 + c0];
        *(short8*)&op[w * 256 + c0] = v;
    }
}

// ---- 256x256 8-phase implicit GEMM, deepened pipeline: vmcnt(8) gate ----
// LDS: 2 buf x 4 sections (A-lo,A-hi,B-lo,B-hi) x 8192 bf16 = 128 KiB.
// All B reads in P0 (+ explicit lgkmcnt(0) before P0-end barrier) => B sections
// are read-quiet after P0, so BOTH A and B stage 2 K-tiles ahead into the
// same-parity buffer; one full K-tile (8 loads) stays in flight across the gate.
__global__ void __launch_bounds__(512)
bconv8(const unsigned short* __restrict__ Xp, const unsigned short* __restrict__ Wt,
       const float* __restrict__ sf, float* __restrict__ out) {
    extern __shared__ unsigned short L[];
    const int tid  = threadIdx.x;
    const int lane = tid & 63, wv = tid >> 6;
    const int wm = wv >> 2, wn = wv & 3;                // wave grid 2M x 4N
    const int bm = blockIdx.x;                          // 392 M-tiles of 256

    // ---- staging addresses (per thread): 2 lane-loads per half-tile ----
    const int r0 = tid >> 3;                            // row-within-64 block
    const int sx = (tid & 7) ^ (r0 & 7);                // pre-swizzled slot
    uint32_t offA[2][2], offB[2][2];                    // [half][i] byte offsets
    #pragma unroll
    for (int hf = 0; hf < 2; ++hf)
        #pragma unroll
        for (int i = 0; i < 2; ++i) {
            int row = hf * 128 + i * 64 + r0;           // row in 256-tile
            int p = bm * 256 + row;                     // M position
            int n = p / 3136, hwp = p - n * 3136;
            int h = hwp / 56,  w = hwp - h * 56;
            offA[hf][i] = (uint32_t)(((((n * 58 + h) * 58 + w) * 256) + sx * 8) * 2);
            offB[hf][i] = (uint32_t)((row * 256 + sx * 8) * 2);
        }
    const uint32_t ldst0 = (uint32_t)wv * 1024u;        // wave-uniform LDS dest

#define STAGE_A(kt, hf, b) do { \
    int _rs = (kt) >> 2; int _dr = _rs / 3, _dc = _rs - _dr * 3; \
    uint32_t _ko = (uint32_t)((_dr * 58 + _dc) * 512 + ((kt) & 3) * 128); \
    uint32_t _lb = (uint32_t)(((b) * 4 + (hf)) * 16384) + ldst0; \
    GLDS((const char*)Xp + offA[hf][0] + _ko, _lb); \
    GLDS((const char*)Xp + offA[hf][1] + _ko, _lb + 8192u); \
} while (0)

#define STAGE_B(kt, hf, b) do { \
    uint32_t _ko = (uint32_t)((kt) >> 2) * 131072u + (uint32_t)(((kt) & 3) * 128); \
    uint32_t _lb = (uint32_t)(((b) * 4 + 2 + (hf)) * 16384) + ldst0; \
    GLDS((const char*)Wt + offB[hf][0] + _ko, _lb); \
    GLDS((const char*)Wt + offB[hf][1] + _ko, _lb + 8192u); \
} while (0)

    // ---- fragment read offsets (elems) ----
    const int rA = lane & 15, hs = lane >> 4, xm = lane & 7;
    const int sl0 = ((hs)     ^ xm) * 8;                // kk=0 swizzled slot
    const int sl1 = ((4 + hs) ^ xm) * 8;                // kk=1

    floatx4 acc[8][4];
    #pragma unroll
    for (int mf = 0; mf < 8; ++mf)
        #pragma unroll
        for (int nf = 0; nf < 4; ++nf) acc[mf][nf] = (floatx4){0.f, 0.f, 0.f, 0.f};

    // ---- prologue: tile0 (8 loads) + tile1 (8 loads); drain tile0 only ----
    STAGE_A(0, 0, 0); STAGE_A(0, 1, 0); STAGE_B(0, 0, 0); STAGE_B(0, 1, 0);
    STAGE_A(1, 0, 1); STAGE_A(1, 1, 1); STAGE_B(1, 0, 1); STAGE_B(1, 1, 1);
    asm volatile("s_waitcnt vmcnt(8)" ::: "memory");    // tile0 resident
    __builtin_amdgcn_s_barrier();

    short8 a0[4][2], a1[4][2], b0[2][2], b1[2][2];

    for (int j = 0; j < NKT; ++j) {
        const int buf = j & 1;
        const uint32_t sA = (uint32_t)(buf * 4 + wm) * 8192u + (uint32_t)(rA * 64);
        const uint32_t sB = (uint32_t)(buf * 4 + 2 + (wn >> 1)) * 8192u
                          + (uint32_t)((wn & 1) * 4096) + (uint32_t)(rA * 64);
        // ---- P0: read A m0 + ALL B; lgkmcnt(0); MFMA (m0,n0) ----
        #pragma unroll
        for (int mf = 0; mf < 4; ++mf) {
            a0[mf][0] = *(const short8*)&L[sA + mf * 1024 + sl0];
            a0[mf][1] = *(const short8*)&L[sA + mf * 1024 + sl1];
        }
        #pragma unroll
        for (int nf = 0; nf < 2; ++nf) {
            b0[nf][0] = *(const short8*)&L[sB + nf * 1024 + sl0];
            b0[nf][1] = *(const short8*)&L[sB + nf * 1024 + sl1];
            b1[nf][0] = *(const short8*)&L[sB + (2 + nf) * 1024 + sl0];
            b1[nf][1] = *(const short8*)&L[sB + (2 + nf) * 1024 + sl1];
        }
        asm volatile("s_waitcnt lgkmcnt(0)" ::: "memory");  // B reads done -> B stage-safe
        __builtin_amdgcn_s_barrier();
        __builtin_amdgcn_s_setprio(1);
        #pragma unroll
        for (int mf = 0; mf < 4; ++mf)
            #pragma unroll
            for (int nf = 0; nf < 2; ++nf) {
                acc[mf][nf] = __builtin_amdgcn_mfma_f32_16x16x32_bf16(a0[mf][0], b0[nf][0], acc[mf][nf], 0, 0, 0);
                acc[mf][nf] = __builtin_amdgcn_mfma_f32_16x16x32_bf16(a0[mf][1], b0[nf][1], acc[mf][nf], 0, 0, 0);
            }
        __builtin_amdgcn_s_setprio(0);
        __builtin_amdgcn_s_barrier();
        // ---- P1: read A m1; stage B-lo(j+2); MFMA (m1,n0) ----
        #pragma unroll
        for (int mf = 0; mf < 4; ++mf) {
            a1[mf][0] = *(const short8*)&L[sA + (4 + mf) * 1024 + sl0];
            a1[mf][1] = *(const short8*)&L[sA + (4 + mf) * 1024 + sl1];
        }
        if (j < NKT - 2) STAGE_B(j + 2, 0, buf);
        __builtin_amdgcn_s_barrier();
        __builtin_amdgcn_s_setprio(1);
        #pragma unroll
        for (int mf = 0; mf < 4; ++mf)
            #pragma unroll
            for (int nf = 0; nf < 2; ++nf) {
                acc[4 + mf][nf] = __builtin_amdgcn_mfma_f32_16x16x32_bf16(a1[mf][0], b0[nf][0], acc[4 + mf][nf], 0, 0, 0);
                acc[4 + mf][nf] = __builtin_amdgcn_mfma_f32_16x16x32_bf16(a1[mf][1], b0[nf][1], acc[4 + mf][nf], 0, 0, 0);
            }
        __builtin_amdgcn_s_setprio(0);
        __builtin_amdgcn_s_barrier();
        // ---- P2: stage B-hi(j+2) + A-lo(j+2); MFMA (m0,n1) ----
        if (j < NKT - 2) { STAGE_B(j + 2, 1, buf); STAGE_A(j + 2, 0, buf); }
        __builtin_amdgcn_s_barrier();
        __builtin_amdgcn_s_setprio(1);
        #pragma unroll
        for (int mf = 0; mf < 4; ++mf)
            #pragma unroll
            for (int nf = 0; nf < 2; ++nf) {
                acc[mf][2 + nf] = __builtin_amdgcn_mfma_f32_16x16x32_bf16(a0[mf][0], b1[nf][0], acc[mf][2 + nf], 0, 0, 0);
                acc[mf][2 + nf] = __builtin_amdgcn_mfma_f32_16x16x32_bf16(a0[mf][1], b1[nf][1], acc[mf][2 + nf], 0, 0, 0);
            }
        __builtin_amdgcn_s_setprio(0);
        __builtin_amdgcn_s_barrier();
        // ---- P3: stage A-hi(j+2); gate vmcnt(8) (tile j+1 resident, j+2 in flight) ----
        if (j < NKT - 2) {
            STAGE_A(j + 2, 1, buf);
            asm volatile("s_waitcnt vmcnt(8)" ::: "memory");
        } else {
            asm volatile("s_waitcnt vmcnt(0)" ::: "memory");
        }
        __builtin_amdgcn_s_barrier();
        __builtin_amdgcn_s_setprio(1);
        #pragma unroll
        for (int mf = 0; mf < 4; ++mf)
            #pragma unroll
            for (int nf = 0; nf < 2; ++nf) {
                acc[4 + mf][2 + nf] = __builtin_amdgcn_mfma_f32_16x16x32_bf16(a1[mf][0], b1[nf][0], acc[4 + mf][2 + nf], 0, 0, 0);
                acc[4 + mf][2 + nf] = __builtin_amdgcn_mfma_f32_16x16x32_bf16(a1[mf][1], b1[nf][1], acc[4 + mf][2 + nf], 0, 0, 0);
            }
        __builtin_amdgcn_s_setprio(0);
        __builtin_amdgcn_s_barrier();
    }

    // ---- epilogue: fused per-channel scale, float4 stores to NCHW ----
    const int p00 = bm * 256 + wm * 128 + hs * 4;
    #pragma unroll
    for (int nf = 0; nf < 4; ++nf) {
        int ko = wn * 64 + nf * 16 + rA;
        float sc = sf[ko];
        #pragma unroll
        for (int mf = 0; mf < 8; ++mf) {
            int p = p00 + mf * 16;
            int ni = p / 3136, hwp = p - ni * 3136;
            floatx4 v = acc[mf][nf];
            floatx4 o = {v.x * sc, v.y * sc, v.z * sc, v.w * sc};
            *(floatx4*)&out[(size_t)ni * 802816 + (size_t)ko * 3136 + hwp] = o;
        }
    }
#undef STAGE_A
#undef STAGE_B
}

// ---- Fallback: naive direct conv (only if ws too small) ----
__global__ void naive_conv(const float* __restrict__ x, const float* __restrict__ wflat,
                           const float* __restrict__ sf, float* __restrict__ out) {
    int idx = blockIdx.x * 256 + threadIdx.x;
    int w = idx % 56, t = idx / 56;
    int h = t % 56; t /= 56;
    int ko = t % 256; int n = t / 256;
    float acc = 0.f;
    for (int c = 0; c < 256; ++c) {
        const float* xc = x + ((size_t)n * 256 + c) * 3136;
        const float* wc = wflat + ((size_t)ko * 256 + c) * 9;
        #pragma unroll
        for (int r = 0; r < 3; ++r) {
            int hh = h + r - 1;
            if (hh < 0 || hh >= 56) continue;
            #pragma unroll
            for (int s = 0; s < 3; ++s) {
                int ww = w + s - 1;
                if (ww < 0 || ww >= 56) continue;
                float wvv = wc[r * 3 + s];
                float sgn = (wvv > 0.f) ? 1.f : ((wvv < 0.f) ? -1.f : 0.f);
                acc += sgn * xc[hh * 56 + ww];
            }
        }
    }
    out[idx] = acc * sf[ko];
}

extern "C" void kernel_launch(void* const* d_in, const int* in_sizes, int n_in,
                              void* d_out, int out_size, void* d_ws, size_t ws_size,
                              hipStream_t stream) {
    const float* x     = (const float*)d_in[0];
    const float* wflat = (const float*)d_in[1];
    const float* sf    = (const float*)d_in[2];
    float* out = (float*)d_out;

    const size_t need = XP_ELEMS * 2 + WT_ELEMS * 2;
    if (ws_size < need) {
        naive_conv<<<(int)(OUT_ELEMS / 256), 256, 0, stream>>>(x, wflat, sf, out);
        return;
    }
    unsigned short* Xp = (unsigned short*)d_ws;
    unsigned short* Wt = Xp + XP_ELEMS;

    (void)hipFuncSetAttribute((const void*)bconv8,
                              hipFuncAttributeMaxDynamicSharedMemorySize, 131072);

    halo_zero<<<(32 * 228 * 128) / 256, 256, 0, stream>>>(Xp);   // 3.7 MB, not 55 MB
    wprep<<<2304, 256, 0, stream>>>(wflat, Wt);
    xprep<<<NIMG * HW, 256, 0, stream>>>(x, Xp);
    bconv8<<<392, 512, 131072, stream>>>(Xp, Wt, sf, out);
}

// Round 6
// 336.893 us; speedup vs baseline: 1.0070x; 1.0070x over previous
//
#include <hip/hip_runtime.h>
#include <hip/hip_bf16.h>
#include <stdint.h>

#define NIMG 32
#define CHN 256
#define HW 56
#define PH 58
#define XP_ELEMS ((size_t)NIMG*PH*PH*CHN)     // 27,557,888 bf16
#define WT_ELEMS ((size_t)9*CHN*CHN)          // 589,824 bf16
#define OUT_ELEMS ((size_t)NIMG*CHN*HW*HW)    // 25,690,112
#define NKT 72                                // K = 2304 = 72 tiles of 32

typedef __attribute__((ext_vector_type(8))) short short8;
typedef __attribute__((ext_vector_type(4))) float floatx4;

#define GLDS(gp, lbyte) __builtin_amdgcn_global_load_lds( \
    (const __attribute__((address_space(1))) void*)(gp), \
    (__attribute__((address_space(3))) void*)((char*)L + (lbyte)), 16, 0, 0)

__device__ inline unsigned short f2bf(float f) {
    union { float f; uint32_t u; } v; v.f = f;
    uint32_t u = v.u;
    return (unsigned short)((u + 0x7FFFu + ((u >> 16) & 1u)) >> 16);  // RNE
}

// ---- weights (flat OIHW fp32) -> sign() bf16, layout [rs][ko][c] ----
__global__ void wprep(const float* __restrict__ wflat, unsigned short* __restrict__ Wt) {
    int o = blockIdx.x * 256 + threadIdx.x;            // < 589824, output-ordered
    int rs = o >> 16, ko = (o >> 8) & 255, c = o & 255;
    float w = wflat[ko * 2304 + c * 9 + rs];
    Wt[o] = (w > 0.f) ? 0x3F80u : (w < 0.f ? 0xBF80u : 0u);
}

// ---- zero only the halo of Xp ----
__global__ void halo_zero(unsigned short* __restrict__ Xp) {
    int idx = blockIdx.x * 256 + threadIdx.x;           // < 32*228*128 (uint writes)
    int c2 = idx & 127;
    int t  = idx >> 7;
    int ci = t % 228, n = t / 228;
    int h, w;
    if (ci < 58)       { h = 0;        w = ci; }
    else if (ci < 116) { h = 57;       w = ci - 58; }
    else if (ci < 172) { h = ci - 115; w = 0; }        // h = 1..56
    else               { h = ci - 171; w = 57; }
    *(uint32_t*)&Xp[(((size_t)n * PH + h) * PH + w) * CHN + c2 * 2] = 0u;
}

// ---- x NCHW fp32 -> padded NHWC bf16 (interior only) ----
__global__ void xprep(const float* __restrict__ x, unsigned short* __restrict__ Xp) {
    __shared__ unsigned short tile[56 * 264];          // pitch 264 (16B-aligned rows)
    int b = blockIdx.x;                                 // one (n,h) row per block
    int n = b / 56, h = b - n * 56;
    const float* xr = x + ((size_t)n * CHN) * (HW*HW) + h * HW;
    int tid = threadIdx.x;
    #pragma unroll 4
    for (int it = 0; it < 28; ++it) {
        int i = it * 256 + tid;                         // (c2, w): c2<128, w<56
        int c2 = i / 56, w = i - c2 * 56, c = c2 * 2;
        float f0 = xr[(size_t)c * 3136 + w];
        float f1 = xr[(size_t)(c + 1) * 3136 + w];
        uint32_t u = (uint32_t)f2bf(f0) | ((uint32_t)f2bf(f1) << 16);
        *(uint32_t*)&tile[w * 264 + c] = u;
    }
    __syncthreads();
    unsigned short* op = Xp + (((size_t)n * PH + (h + 1)) * PH + 1) * CHN;
    #pragma unroll
    for (int it = 0; it < 7; ++it) {
        int chunk = it * 256 + tid;
        int w = chunk >> 5, c0 = (chunk & 31) * 8;
        short8 v = *(const short8*)&tile[w * 264 + c0];
        *(short8*)&op[w * 256 + c0] = v;
    }
}

// ---- 256x256 implicit GEMM, BK=32, 64 KiB LDS -> 2 blocks/CU ----
// LDS per buf: A[256][32] (16 KB) + B[256][32] (16 KB); 2 bufs = 64 KiB.
// Pure double-buffer: iter j reads buf, stages tile j+1 into buf^1 (no
// same-buffer hazards). Gate vmcnt(0) at iter end (cover ~2 phases); the
// co-resident partner block masks residual latency + barrier stalls.
// Swizzle (rule 21): slot' = slot ^ (row&3); bijective 1 KiB per wave read.
__global__ void __launch_bounds__(512)
bconv8(const unsigned short* __restrict__ Xp, const unsigned short* __restrict__ Wt,
       const float* __restrict__ sf, float* __restrict__ out) {
    extern __shared__ unsigned short L[];
    const int tid  = threadIdx.x;
    const int lane = tid & 63, wv = tid >> 6;
    const int wm = wv >> 2, wn = wv & 3;                // wave grid 2M x 4N
    const int bm = blockIdx.x;                          // 392 M-tiles of 256

    // ---- staging addresses: 2 loadsets of 128 rows; 4 slots of 8 elems ----
    const int r0 = tid >> 2;                            // row 0..127 within loadset
    const int sx = (tid & 3) ^ (r0 & 3);                // pre-swizzled slot
    uint32_t offA[2], offB[2];
    #pragma unroll
    for (int i = 0; i < 2; ++i) {
        int row = i * 128 + r0;                         // row in 256-tile
        int p = bm * 256 + row;                         // M position
        int n = p / 3136, hwp = p - n * 3136;
        int h = hwp / 56,  w = hwp - h * 56;
        offA[i] = (uint32_t)(((((n * 58 + h) * 58 + w) * 256) + sx * 8) * 2);
        offB[i] = (uint32_t)((row * 256 + sx * 8) * 2);
    }
    const uint32_t ldst0 = (uint32_t)wv * 1024u;        // wave-uniform LDS dest

#define KOA(kt) ({ int _rs = (kt) >> 3; int _dr = _rs / 3, _dc = _rs - _dr * 3; \
                   (uint32_t)((_dr * 58 + _dc) * 512 + ((kt) & 7) * 64); })
#define KOB(kt) ((uint32_t)(((kt) >> 3) * 131072 + ((kt) & 7) * 64))

#define STAGE_A(kt, b) do { uint32_t _k = KOA(kt); \
    GLDS((const char*)Xp + offA[0] + _k, (uint32_t)(b) * 32768u + ldst0); \
    GLDS((const char*)Xp + offA[1] + _k, (uint32_t)(b) * 32768u + 8192u + ldst0); \
} while (0)

#define STAGE_B(kt, b) do { uint32_t _k = KOB(kt); \
    GLDS((const char*)Wt + offB[0] + _k, (uint32_t)(b) * 32768u + 16384u + ldst0); \
    GLDS((const char*)Wt + offB[1] + _k, (uint32_t)(b) * 32768u + 24576u + ldst0); \
} while (0)

    // ---- fragment read offsets (ushort elems) ----
    const int rA = lane & 15, hs = lane >> 4;
    const int slX = (hs ^ (rA & 3)) * 8;                // swizzled k-slot

    floatx4 acc[8][4];
    #pragma unroll
    for (int mf = 0; mf < 8; ++mf)
        #pragma unroll
        for (int nf = 0; nf < 4; ++nf) acc[mf][nf] = (floatx4){0.f, 0.f, 0.f, 0.f};

    // ---- prologue: tile0 -> buf0 ----
    STAGE_A(0, 0); STAGE_B(0, 0);
    asm volatile("s_waitcnt vmcnt(0)" ::: "memory");
    __builtin_amdgcn_s_barrier();

    short8 a0[4], a1[4], bfr[4];

    for (int j = 0; j < NKT; ++j) {
        const int buf = j & 1, nb = buf ^ 1;
        const uint32_t sAe = (uint32_t)(buf * 16384) + (uint32_t)((wm * 128 + rA) * 32) + slX;
        const uint32_t sBe = (uint32_t)(buf * 16384 + 8192) + (uint32_t)((wn * 64 + rA) * 32) + slX;
        // ---- P0: read A m0-3 + all B; stage tile j+1; MFMA (m0-3, all n) ----
        #pragma unroll
        for (int mf = 0; mf < 4; ++mf) a0[mf] = *(const short8*)&L[sAe + mf * 512];
        #pragma unroll
        for (int nf = 0; nf < 4; ++nf) bfr[nf] = *(const short8*)&L[sBe + nf * 512];
        if (j < NKT - 1) { STAGE_A(j + 1, nb); STAGE_B(j + 1, nb); }
        __builtin_amdgcn_s_barrier();
        __builtin_amdgcn_s_setprio(1);
        #pragma unroll
        for (int mf = 0; mf < 4; ++mf)
            #pragma unroll
            for (int nf = 0; nf < 4; ++nf)
                acc[mf][nf] = __builtin_amdgcn_mfma_f32_16x16x32_bf16(a0[mf], bfr[nf], acc[mf][nf], 0, 0, 0);
        __builtin_amdgcn_s_setprio(0);
        __builtin_amdgcn_s_barrier();
        // ---- P1: read A m4-7; MFMA (m4-7, all n); gate j+1 resident ----
        #pragma unroll
        for (int mf = 0; mf < 4; ++mf) a1[mf] = *(const short8*)&L[sAe + (4 + mf) * 512];
        __builtin_amdgcn_s_setprio(1);
        #pragma unroll
        for (int mf = 0; mf < 4; ++mf)
            #pragma unroll
            for (int nf = 0; nf < 4; ++nf)
                acc[4 + mf][nf] = __builtin_amdgcn_mfma_f32_16x16x32_bf16(a1[mf], bfr[nf], acc[4 + mf][nf], 0, 0, 0);
        __builtin_amdgcn_s_setprio(0);
        asm volatile("s_waitcnt vmcnt(0)" ::: "memory");  // tile j+1 resident
        __builtin_amdgcn_s_barrier();
    }

    // ---- epilogue: fused per-channel scale, float4 stores to NCHW ----
    const int p00 = bm * 256 + wm * 128 + hs * 4;
    #pragma unroll
    for (int nf = 0; nf < 4; ++nf) {
        int ko = wn * 64 + nf * 16 + rA;
        float sc = sf[ko];
        #pragma unroll
        for (int mf = 0; mf < 8; ++mf) {
            int p = p00 + mf * 16;
            int ni = p / 3136, hwp = p - ni * 3136;
            floatx4 v = acc[mf][nf];
            floatx4 o = {v.x * sc, v.y * sc, v.z * sc, v.w * sc};
            *(floatx4*)&out[(size_t)ni * 802816 + (size_t)ko * 3136 + hwp] = o;
        }
    }
#undef STAGE_A
#undef STAGE_B
#undef KOA
#undef KOB
}

// ---- Fallback: naive direct conv (only if ws too small) ----
__global__ void naive_conv(const float* __restrict__ x, const float* __restrict__ wflat,
                           const float* __restrict__ sf, float* __restrict__ out) {
    int idx = blockIdx.x * 256 + threadIdx.x;
    int w = idx % 56, t = idx / 56;
    int h = t % 56; t /= 56;
    int ko = t % 256; int n = t / 256;
    float acc = 0.f;
    for (int c = 0; c < 256; ++c) {
        const float* xc = x + ((size_t)n * 256 + c) * 3136;
        const float* wc = wflat + ((size_t)ko * 256 + c) * 9;
        #pragma unroll
        for (int r = 0; r < 3; ++r) {
            int hh = h + r - 1;
            if (hh < 0 || hh >= 56) continue;
            #pragma unroll
            for (int s = 0; s < 3; ++s) {
                int ww = w + s - 1;
                if (ww < 0 || ww >= 56) continue;
                float wvv = wc[r * 3 + s];
                float sgn = (wvv > 0.f) ? 1.f : ((wvv < 0.f) ? -1.f : 0.f);
                acc += sgn * xc[hh * 56 + ww];
            }
        }
    }
    out[idx] = acc * sf[ko];
}

extern "C" void kernel_launch(void* const* d_in, const int* in_sizes, int n_in,
                              void* d_out, int out_size, void* d_ws, size_t ws_size,
                              hipStream_t stream) {
    const float* x     = (const float*)d_in[0];
    const float* wflat = (const float*)d_in[1];
    const float* sf    = (const float*)d_in[2];
    float* out = (float*)d_out;

    const size_t need = XP_ELEMS * 2 + WT_ELEMS * 2;
    if (ws_size < need) {
        naive_conv<<<(int)(OUT_ELEMS / 256), 256, 0, stream>>>(x, wflat, sf, out);
        return;
    }
    unsigned short* Xp = (unsigned short*)d_ws;
    unsigned short* Wt = Xp + XP_ELEMS;

    (void)hipFuncSetAttribute((const void*)bconv8,
                              hipFuncAttributeMaxDynamicSharedMemorySize, 65536);

    halo_zero<<<(32 * 228 * 128) / 256, 256, 0, stream>>>(Xp);
    wprep<<<2304, 256, 0, stream>>>(wflat, Wt);
    xprep<<<NIMG * HW, 256, 0, stream>>>(x, Xp);
    bconv8<<<392, 512, 65536, stream>>>(Xp, Wt, sf, out);
}

// Round 8
// 322.352 us; speedup vs baseline: 1.0524x; 1.0451x over previous
//
#include <hip/hip_runtime.h>
#include <hip/hip_bf16.h>
#include <stdint.h>

#define NIMG 32
#define CHN 256
#define HW 56
#define PH 58
#define XP_ELEMS ((size_t)NIMG*PH*PH*CHN)     // 27,557,888 bf16
#define WT_ELEMS ((size_t)9*CHN*CHN)          // 589,824 bf16
#define OUT_ELEMS ((size_t)NIMG*CHN*HW*HW)    // 25,690,112
#define NKT 36                                // K = 2304 = 36 tiles of 64
#define BM 224                                // 100352 = 224 * 448 -> grid 448
#define NBLK 448

typedef __attribute__((ext_vector_type(8))) short short8;
typedef __attribute__((ext_vector_type(4))) float floatx4;

#define GLDS(gp, lbyte) __builtin_amdgcn_global_load_lds( \
    (const __attribute__((address_space(1))) void*)(gp), \
    (__attribute__((address_space(3))) void*)((char*)L + (lbyte)), 16, 0, 0)

__device__ inline unsigned short f2bf(float f) {
    union { float f; uint32_t u; } v; v.f = f;
    uint32_t u = v.u;
    return (unsigned short)((u + 0x7FFFu + ((u >> 16) & 1u)) >> 16);  // RNE
}

// ---- weights (flat OIHW fp32) -> sign() bf16, layout [rs][ko][c] ----
__global__ void wprep(const float* __restrict__ wflat, unsigned short* __restrict__ Wt) {
    int o = blockIdx.x * 256 + threadIdx.x;            // < 589824, output-ordered
    int rs = o >> 16, ko = (o >> 8) & 255, c = o & 255;
    float w = wflat[ko * 2304 + c * 9 + rs];
    Wt[o] = (w > 0.f) ? 0x3F80u : (w < 0.f ? 0xBF80u : 0u);
}

// ---- zero only the halo of Xp ----
__global__ void halo_zero(unsigned short* __restrict__ Xp) {
    int idx = blockIdx.x * 256 + threadIdx.x;           // < 32*228*128 (uint writes)
    int c2 = idx & 127;
    int t  = idx >> 7;
    int ci = t % 228, n = t / 228;
    int h, w;
    if (ci < 58)       { h = 0;        w = ci; }
    else if (ci < 116) { h = 57;       w = ci - 58; }
    else if (ci < 172) { h = ci - 115; w = 0; }        // h = 1..56
    else               { h = ci - 171; w = 57; }
    *(uint32_t*)&Xp[(((size_t)n * PH + h) * PH + w) * CHN + c2 * 2] = 0u;
}

// ---- x NCHW fp32 -> padded NHWC bf16 (interior only) ----
__global__ void xprep(const float* __restrict__ x, unsigned short* __restrict__ Xp) {
    __shared__ unsigned short tile[56 * 264];          // pitch 264 (16B-aligned rows)
    int b = blockIdx.x;                                 // one (n,h) row per block
    int n = b / 56, h = b - n * 56;
    const float* xr = x + ((size_t)n * CHN) * (HW*HW) + h * HW;
    int tid = threadIdx.x;
    #pragma unroll 4
    for (int it = 0; it < 28; ++it) {
        int i = it * 256 + tid;                         // (c2, w): c2<128, w<56
        int c2 = i / 56, w = i - c2 * 56, c = c2 * 2;
        float f0 = xr[(size_t)c * 3136 + w];
        float f1 = xr[(size_t)(c + 1) * 3136 + w];
        uint32_t u = (uint32_t)f2bf(f0) | ((uint32_t)f2bf(f1) << 16);
        *(uint32_t*)&tile[w * 264 + c] = u;
    }
    __syncthreads();
    unsigned short* op = Xp + (((size_t)n * PH + (h + 1)) * PH + 1) * CHN;
    #pragma unroll
    for (int it = 0; it < 7; ++it) {
        int chunk = it * 256 + tid;
        int w = chunk >> 5, c0 = (chunk & 31) * 8;
        short8 v = *(const short8*)&tile[w * 264 + c0];
        *(short8*)&op[w * 256 + c0] = v;
    }
}

// ---- 224x256 8-phase implicit GEMM (R4 schedule, BM=224 for tail fix) ----
// LDS: 2 buf x [A-lo 16K | A-hi 16K | B-lo 16K | B-hi 16K] = 128 KiB.
// A halves hold 112 rows (14336 B used, padded to 16384). Staging: 64 rows by
// all 8 waves + 48 rows by waves 0-5; waves 6-7 issue a DUMMY gload into the
// padding so every wave's vmcnt count stays uniform (gate vmcnt(4) as R4).
// Swizzle (rule 21): 128-B rows, slot ^= row&7 both sides (R4: 0 conflicts).
__global__ void __launch_bounds__(512)
bconv8(const unsigned short* __restrict__ Xp, const unsigned short* __restrict__ Wt,
       const float* __restrict__ sf, float* __restrict__ out) {
    extern __shared__ unsigned short L[];
    const int tid  = threadIdx.x;
    const int lane = tid & 63, wv = tid >> 6;
    const int wm = wv >> 2, wn = wv & 3;                // wave grid 2M x 4N
    const int bm = blockIdx.x;                          // 448 M-tiles of 224

    // ---- staging addresses ----
    const int r0 = tid >> 3;                            // 0..63
    const int sx = (tid & 7) ^ (r0 & 7);                // pre-swizzled slot
    uint32_t offA[2][2], offB[2][2];
    #pragma unroll
    for (int hf = 0; hf < 2; ++hf)
        #pragma unroll
        for (int i = 0; i < 2; ++i) {
            int rowA = hf * 112 + i * 64 + r0;          // A row (i=1 used by wv<6)
            if (rowA > 223) rowA = 223;                 // clamp (unused lanes)
            int p = bm * BM + rowA;
            int n = p / 3136, hwp = p - n * 3136;
            int h = hwp / 56,  w = hwp - h * 56;
            offA[hf][i] = (uint32_t)(((((n * 58 + h) * 58 + w) * 256) + sx * 8) * 2);
            int rowB = hf * 128 + i * 64 + r0;          // B row (ko)
            offB[hf][i] = (uint32_t)((rowB * 256 + sx * 8) * 2);
        }
    const uint32_t wv1k = (uint32_t)wv * 1024u;

#define KOA(kt) ({ int _rs = (kt) >> 2; int _dr = _rs / 3, _dc = _rs - _dr * 3; \
                   (uint32_t)((_dr * 58 + _dc) * 512 + ((kt) & 3) * 128); })
#define KOB(kt) ((uint32_t)(((kt) >> 2) * 131072 + ((kt) & 3) * 128))

#define STAGE_A(kt, hf, b) do { uint32_t _k = KOA(kt); \
    uint32_t _sec = (uint32_t)(b) * 65536u + (uint32_t)(hf) * 16384u; \
    GLDS((const char*)Xp + offA[hf][0] + _k, _sec + wv1k); \
    if (wv < 6) GLDS((const char*)Xp + offA[hf][1] + _k, _sec + 8192u + wv1k); \
    else        GLDS((const char*)Xp + offA[hf][0] + _k, _sec + 8192u + wv1k); /* dummy -> 14336/15360 pad */ \
} while (0)

#define STAGE_B(kt, hf, b) do { uint32_t _k = KOB(kt); \
    uint32_t _sec = (uint32_t)(b) * 65536u + 32768u + (uint32_t)(hf) * 16384u; \
    GLDS((const char*)Wt + offB[hf][0] + _k, _sec + wv1k); \
    GLDS((const char*)Wt + offB[hf][1] + _k, _sec + 8192u + wv1k); \
} while (0)

    // ---- fragment read offsets (elems) ----
    const int rA = lane & 15, hs = lane >> 4, xm = lane & 7;
    const int sl0 = ((hs)     ^ xm) * 8;                // kk=0 swizzled slot
    const int sl1 = ((4 + hs) ^ xm) * 8;                // kk=1

    floatx4 acc[7][4];
    #pragma unroll
    for (int mf = 0; mf < 7; ++mf)
        #pragma unroll
        for (int nf = 0; nf < 4; ++nf) acc[mf][nf] = (floatx4){0.f, 0.f, 0.f, 0.f};

    // ---- prologue: tile0 full + tile1 A halves; drain tile0, keep tile1-A ----
    STAGE_A(0, 0, 0); STAGE_A(0, 1, 0); STAGE_B(0, 0, 0); STAGE_B(0, 1, 0);
    STAGE_A(1, 0, 1); STAGE_A(1, 1, 1);
    asm volatile("s_waitcnt vmcnt(4)" ::: "memory");    // tile0 resident
    __builtin_amdgcn_s_barrier();

    short8 a0[4][2], a1[3][2], b0[2][2], b1[2][2];

    for (int j = 0; j < NKT; ++j) {
        const int buf = j & 1, ob = buf ^ 1;
        const uint32_t sA = (uint32_t)buf * 32768u + (uint32_t)wm * 8192u + (uint32_t)(rA * 64);
        const uint32_t sB = (uint32_t)buf * 32768u + 16384u + (uint32_t)((wn >> 1) * 8192)
                          + (uint32_t)((wn & 1) * 4096) + (uint32_t)(rA * 64);
        // ---- P0: read A m0-3 + B n0; stage B-lo(j+1); MFMA (m0-3,n0) ----
        #pragma unroll
        for (int mf = 0; mf < 4; ++mf) {
            a0[mf][0] = *(const short8*)&L[sA + mf * 1024 + sl0];
            a0[mf][1] = *(const short8*)&L[sA + mf * 1024 + sl1];
        }
        #pragma unroll
        for (int nf = 0; nf < 2; ++nf) {
            b0[nf][0] = *(const short8*)&L[sB + nf * 1024 + sl0];
            b0[nf][1] = *(const short8*)&L[sB + nf * 1024 + sl1];
        }
        if (j < NKT - 1) STAGE_B(j + 1, 0, ob);
        __builtin_amdgcn_s_barrier();
        __builtin_amdgcn_s_setprio(1);
        #pragma unroll
        for (int mf = 0; mf < 4; ++mf)
            #pragma unroll
            for (int nf = 0; nf < 2; ++nf) {
                acc[mf][nf] = __builtin_amdgcn_mfma_f32_16x16x32_bf16(a0[mf][0], b0[nf][0], acc[mf][nf], 0, 0, 0);
                acc[mf][nf] = __builtin_amdgcn_mfma_f32_16x16x32_bf16(a0[mf][1], b0[nf][1], acc[mf][nf], 0, 0, 0);
            }
        __builtin_amdgcn_s_setprio(0);
        __builtin_amdgcn_s_barrier();
        // ---- P1: read A m4-6; stage B-hi(j+1); MFMA (m4-6,n0) ----
        #pragma unroll
        for (int mf = 0; mf < 3; ++mf) {
            a1[mf][0] = *(const short8*)&L[sA + (4 + mf) * 1024 + sl0];
            a1[mf][1] = *(const short8*)&L[sA + (4 + mf) * 1024 + sl1];
        }
        if (j < NKT - 1) STAGE_B(j + 1, 1, ob);
        __builtin_amdgcn_s_barrier();
        __builtin_amdgcn_s_setprio(1);
        #pragma unroll
        for (int mf = 0; mf < 3; ++mf)
            #pragma unroll
            for (int nf = 0; nf < 2; ++nf) {
                acc[4 + mf][nf] = __builtin_amdgcn_mfma_f32_16x16x32_bf16(a1[mf][0], b0[nf][0], acc[4 + mf][nf], 0, 0, 0);
                acc[4 + mf][nf] = __builtin_amdgcn_mfma_f32_16x16x32_bf16(a1[mf][1], b0[nf][1], acc[4 + mf][nf], 0, 0, 0);
            }
        __builtin_amdgcn_s_setprio(0);
        __builtin_amdgcn_s_barrier();
        // ---- P2: read B n1; stage A-lo(j+2); MFMA (m0-3,n1) ----
        #pragma unroll
        for (int nf = 0; nf < 2; ++nf) {
            b1[nf][0] = *(const short8*)&L[sB + (2 + nf) * 1024 + sl0];
            b1[nf][1] = *(const short8*)&L[sB + (2 + nf) * 1024 + sl1];
        }
        if (j < NKT - 2) STAGE_A(j + 2, 0, buf);
        __builtin_amdgcn_s_barrier();
        __builtin_amdgcn_s_setprio(1);
        #pragma unroll
        for (int mf = 0; mf < 4; ++mf)
            #pragma unroll
            for (int nf = 0; nf < 2; ++nf) {
                acc[mf][2 + nf] = __builtin_amdgcn_mfma_f32_16x16x32_bf16(a0[mf][0], b1[nf][0], acc[mf][2 + nf], 0, 0, 0);
                acc[mf][2 + nf] = __builtin_amdgcn_mfma_f32_16x16x32_bf16(a0[mf][1], b1[nf][1], acc[mf][2 + nf], 0, 0, 0);
            }
        __builtin_amdgcn_s_setprio(0);
        __builtin_amdgcn_s_barrier();
        // ---- P3: stage A-hi(j+2); gate vmcnt(4); MFMA (m4-6,n1) ----
        if (j < NKT - 2) {
            STAGE_A(j + 2, 1, buf);
            asm volatile("s_waitcnt vmcnt(4)" ::: "memory");  // tile j+1 resident
        } else {
            asm volatile("s_waitcnt vmcnt(0)" ::: "memory");
        }
        __builtin_amdgcn_s_barrier();
        __builtin_amdgcn_s_setprio(1);
        #pragma unroll
        for (int mf = 0; mf < 3; ++mf)
            #pragma unroll
            for (int nf = 0; nf < 2; ++nf) {
                acc[4 + mf][2 + nf] = __builtin_amdgcn_mfma_f32_16x16x32_bf16(a1[mf][0], b1[nf][0], acc[4 + mf][2 + nf], 0, 0, 0);
                acc[4 + mf][2 + nf] = __builtin_amdgcn_mfma_f32_16x16x32_bf16(a1[mf][1], b1[nf][1], acc[4 + mf][2 + nf], 0, 0, 0);
            }
        __builtin_amdgcn_s_setprio(0);
        __builtin_amdgcn_s_barrier();
    }

    // ---- epilogue: fused per-channel scale, float4 stores to NCHW ----
    const int p00 = bm * BM + wm * 112 + hs * 4;
    #pragma unroll
    for (int nf = 0; nf < 4; ++nf) {
        int ko = wn * 64 + nf * 16 + rA;
        float sc = sf[ko];
        #pragma unroll
        for (int mf = 0; mf < 7; ++mf) {
            int p = p00 + mf * 16;
            int ni = p / 3136, hwp = p - ni * 3136;
            floatx4 v = acc[mf][nf];
            floatx4 o = {v.x * sc, v.y * sc, v.z * sc, v.w * sc};
            *(floatx4*)&out[(size_t)ni * 802816 + (size_t)ko * 3136 + hwp] = o;
        }
    }
#undef STAGE_A
#undef STAGE_B
#undef KOA
#undef KOB
}

// ---- Fallback: naive direct conv (only if ws too small) ----
__global__ void naive_conv(const float* __restrict__ x, const float* __restrict__ wflat,
                           const float* __restrict__ sf, float* __restrict__ out) {
    int idx = blockIdx.x * 256 + threadIdx.x;
    int w = idx % 56, t = idx / 56;
    int h = t % 56; t /= 56;
    int ko = t % 256; int n = t / 256;
    float acc = 0.f;
    for (int c = 0; c < 256; ++c) {
        const float* xc = x + ((size_t)n * 256 + c) * 3136;
        const float* wc = wflat + ((size_t)ko * 256 + c) * 9;
        #pragma unroll
        for (int r = 0; r < 3; ++r) {
            int hh = h + r - 1;
            if (hh < 0 || hh >= 56) continue;
            #pragma unroll
            for (int s = 0; s < 3; ++s) {
                int ww = w + s - 1;
                if (ww < 0 || ww >= 56) continue;
                float wvv = wc[r * 3 + s];
                float sgn = (wvv > 0.f) ? 1.f : ((wvv < 0.f) ? -1.f : 0.f);
                acc += sgn * xc[hh * 56 + ww];
            }
        }
    }
    out[idx] = acc * sf[ko];
}

extern "C" void kernel_launch(void* const* d_in, const int* in_sizes, int n_in,
                              void* d_out, int out_size, void* d_ws, size_t ws_size,
                              hipStream_t stream) {
    const float* x     = (const float*)d_in[0];
    const float* wflat = (const float*)d_in[1];
    const float* sf    = (const float*)d_in[2];
    float* out = (float*)d_out;

    const size_t need = XP_ELEMS * 2 + WT_ELEMS * 2;
    if (ws_size < need) {
        naive_conv<<<(int)(OUT_ELEMS / 256), 256, 0, stream>>>(x, wflat, sf, out);
        return;
    }
    unsigned short* Xp = (unsigned short*)d_ws;
    unsigned short* Wt = Xp + XP_ELEMS;

    (void)hipFuncSetAttribute((const void*)bconv8,
                              hipFuncAttributeMaxDynamicSharedMemorySize, 131072);

    halo_zero<<<(32 * 228 * 128) / 256, 256, 0, stream>>>(Xp);
    wprep<<<2304, 256, 0, stream>>>(wflat, Wt);
    xprep<<<NIMG * HW, 256, 0, stream>>>(x, Xp);
    bconv8<<<NBLK, 512, 131072, stream>>>(Xp, Wt, sf, out);
}